// Round 10
// baseline (101.875 us; speedup 1.0000x reference)
//
#include <hip/hip_runtime.h>

// B=2, T=2048, D_IN=D_OUT=512, H=8, DK=64
constexpr int B_   = 2;
constexpr int T_   = 2048;
constexpr int DIN  = 512;
constexpr int DOUT = 512;
constexpr int H_   = 8;
constexpr int DK_  = 64;

typedef float    f32x16  __attribute__((ext_vector_type(16)));
typedef short    short8v __attribute__((ext_vector_type(8)));
typedef __bf16   bf16x8  __attribute__((ext_vector_type(8)));

__device__ inline f32x16 mfma3216(short8v a, short8v b, f32x16 c) {
    return __builtin_amdgcn_mfma_f32_32x32x16_bf16(
        __builtin_bit_cast(bf16x8, a), __builtin_bit_cast(bf16x8, b), c, 0, 0, 0);
}

__device__ inline unsigned short bf16c(float f) {
    return __builtin_bit_cast(unsigned short, (__bf16)f);
}
__device__ inline float bf2f(unsigned short u) {
    return (float)__builtin_bit_cast(__bf16, u);
}
__device__ inline unsigned pk2(float lo, float hi) {
    return (unsigned)bf16c(lo) | ((unsigned)bf16c(hi) << 16);
}

// ---------------------------------------------------------------------------
// Weight conversion only: Wq,Wk,Wv,Wo f32 -> bf16 hi + bf16 lo. 256 blocks.
// (r6 verbatim)
// ---------------------------------------------------------------------------
__global__ __launch_bounds__(256) void wconvert_kernel(
    const float* __restrict__ Wq, const float* __restrict__ Wk,
    const float* __restrict__ Wv, const float* __restrict__ Wo,
    unsigned short* __restrict__ Wh, unsigned short* __restrict__ Wl)
{
    const int b = blockIdx.x, t = threadIdx.x;
    const int wi = b >> 6;
    const float* src = wi == 0 ? Wq : (wi == 1 ? Wk : (wi == 2 ? Wv : Wo));
    unsigned short* hi = Wh + (size_t)wi * 262144;
    unsigned short* lo = Wl + (size_t)wi * 262144;
    const size_t off = (size_t)(b & 63) * 4096;
#pragma unroll
    for (int c = 0; c < 4; ++c) {
        const size_t idx = off + (size_t)c * 1024 + (size_t)t * 4;
        const float4 x = *(const float4*)&src[idx];
        ushort4 h;
        h.x = bf16c(x.x); h.y = bf16c(x.y); h.z = bf16c(x.z); h.w = bf16c(x.w);
        *(ushort4*)&hi[idx] = h;
        ushort4 l2;
        l2.x = bf16c(x.x - bf2f(h.x));
        l2.y = bf16c(x.y - bf2f(h.y));
        l2.z = bf16c(x.z - bf2f(h.z));
        l2.w = bf16c(x.w - bf2f(h.w));
        *(ushort4*)&lo[idx] = l2;
    }
}

// ---------------------------------------------------------------------------
// Epilogue store: MODE 0 f32 [M,N]; 1 bf16 [B,H,T,DK]; 3 K-frag; 4 V-frag.
// ---------------------------------------------------------------------------
template<int MODE>
__device__ __forceinline__ void store_c(unsigned short* __restrict__ outb,
                                        float* __restrict__ outf,
                                        int m, int n, float v)
{
    if constexpr (MODE == 0) {
        outf[(size_t)m * DOUT + n] = v;
    } else {
        const int bb = m >> 11, t = m & (T_ - 1);
        const int hh = n >> 6,  d = n & (DK_ - 1);
        const size_t bh = (size_t)bb * H_ + hh;
        if constexpr (MODE == 1) {
            outb[(bh * T_ + t) * DK_ + d] = bf16c(v);
        } else if constexpr (MODE == 3) {
            // K-frag: [bh][kt][c*2+khi][l31][8]
            const int kt = t >> 5, l31 = t & 31;
            const int c = d >> 4, khi = (d >> 3) & 1, e = d & 7;
            outb[(bh * 64 + kt) * 2048 + (c * 2 + khi) * 256 + l31 * 8 + e] = bf16c(v);
        } else {
            // V-frag: [bh][kt][(kgrp*2+dblk)*2+khi][l31][8]
            const int kt = t >> 5, kgrp = (t >> 4) & 1, khi = (t >> 3) & 1, e = t & 7;
            const int dblk = d >> 5, l31 = d & 31;
            outb[(bh * 64 + kt) * 2048 + ((kgrp * 2 + dblk) * 2 + khi) * 256 + l31 * 8 + e] = bf16c(v);
        }
    }
}

// ---------------------------------------------------------------------------
// MFMA GEMM (r7 form — exonerated bit-neutral by the r7/r8 identity):
// out = A @ (Wh+Wl)^T + bias.  BM=128, BN=64 or 128, BK=32, 4 waves.
// Single LDS buffer, two barriers per K-step, reg-prefetch of step kb+1
// issued between stage-barrier and compute.
// LDS XOR-swizzle: 16B chunk pos ^= (row>>1)&3.
// ---------------------------------------------------------------------------
template<int MODE, bool AF32, int BN>
__device__ inline void gemm_body(
    const void* __restrict__ Av, const unsigned short* __restrict__ Bhp,
    const unsigned short* __restrict__ Blp, const float* __restrict__ bias,
    unsigned short* __restrict__ outb, float* __restrict__ outf)
{
    __shared__ unsigned short As[128 * 32];
    __shared__ unsigned short Bsh[BN * 32];
    __shared__ unsigned short Bsl[BN * 32];

    const int tid = threadIdx.x;
    const int m0 = blockIdx.y * 128, n0 = blockIdx.x * BN;
    const int lane31 = tid & 31, hi8 = (tid & 63) >> 5;
    const int wv = tid >> 6, wm = wv >> 1, wn = wv & 1;

    const int r_  = tid >> 2, pos_ = tid & 3;
    const int r2_ = r_ + 64;
    const int sw_  = pos_ ^ ((r_  >> 1) & 3);
    const int sw2_ = pos_ ^ ((r2_ >> 1) & 3);

    short8v a0r, a1r, bh0r, bl0r, bh1r, bl1r;

    auto gload = [&](int kb) {
        const int k0 = kb * 32;
        if constexpr (AF32) {
            const float* Af = (const float*)Av;
            {
                const float4 f0 = *(const float4*)&Af[(size_t)(m0 + r_) * DIN + k0 + pos_ * 8];
                const float4 f1 = *(const float4*)&Af[(size_t)(m0 + r_) * DIN + k0 + pos_ * 8 + 4];
                union { unsigned w[4]; short8v v; } u;
                u.w[0] = pk2(f0.x, f0.y); u.w[1] = pk2(f0.z, f0.w);
                u.w[2] = pk2(f1.x, f1.y); u.w[3] = pk2(f1.z, f1.w);
                a0r = u.v;
            }
            {
                const float4 f0 = *(const float4*)&Af[(size_t)(m0 + r2_) * DIN + k0 + pos_ * 8];
                const float4 f1 = *(const float4*)&Af[(size_t)(m0 + r2_) * DIN + k0 + pos_ * 8 + 4];
                union { unsigned w[4]; short8v v; } u;
                u.w[0] = pk2(f0.x, f0.y); u.w[1] = pk2(f0.z, f0.w);
                u.w[2] = pk2(f1.x, f1.y); u.w[3] = pk2(f1.z, f1.w);
                a1r = u.v;
            }
        } else {
            const unsigned short* Ab = (const unsigned short*)Av;
            a0r = *(const short8v*)&Ab[(size_t)(m0 + r_)  * DIN + k0 + pos_ * 8];
            a1r = *(const short8v*)&Ab[(size_t)(m0 + r2_) * DIN + k0 + pos_ * 8];
        }
        bh0r = *(const short8v*)&Bhp[(size_t)(n0 + r_) * DIN + k0 + pos_ * 8];
        bl0r = *(const short8v*)&Blp[(size_t)(n0 + r_) * DIN + k0 + pos_ * 8];
        if constexpr (BN == 128) {
            bh1r = *(const short8v*)&Bhp[(size_t)(n0 + r2_) * DIN + k0 + pos_ * 8];
            bl1r = *(const short8v*)&Blp[(size_t)(n0 + r2_) * DIN + k0 + pos_ * 8];
        }
    };
    auto swrite = [&]() {
        *(short8v*)((char*)As + r_  * 64 + sw_  * 16) = a0r;
        *(short8v*)((char*)As + r2_ * 64 + sw2_ * 16) = a1r;
        *(short8v*)((char*)Bsh + r_ * 64 + sw_ * 16) = bh0r;
        *(short8v*)((char*)Bsl + r_ * 64 + sw_ * 16) = bl0r;
        if constexpr (BN == 128) {
            *(short8v*)((char*)Bsh + r2_ * 64 + sw2_ * 16) = bh1r;
            *(short8v*)((char*)Bsl + r2_ * 64 + sw2_ * 16) = bl1r;
        }
    };

    f32x16 acc00 = {}, acc01 = {}, acc10 = {}, acc11 = {};

    gload(0);
    for (int kb = 0; kb < 16; ++kb) {
        swrite();
        __syncthreads();
        if (kb < 15) gload(kb + 1);       // prefetch next step during compute
#pragma unroll
        for (int ks = 0; ks < 2; ++ks) {
            const int pos = ks * 2 + hi8;
            short8v a0, a1;
            { const int r = wm * 64 + lane31;
              a0 = *(const short8v*)((char*)As + r * 64 + ((pos ^ ((r >> 1) & 3)) << 4)); }
            { const int r = wm * 64 + 32 + lane31;
              a1 = *(const short8v*)((char*)As + r * 64 + ((pos ^ ((r >> 1) & 3)) << 4)); }
            if constexpr (BN == 64) {
                short8v b0h, b0l;
                { const int r = wn * 32 + lane31;
                  b0h = *(const short8v*)((char*)Bsh + r * 64 + ((pos ^ ((r >> 1) & 3)) << 4));
                  b0l = *(const short8v*)((char*)Bsl + r * 64 + ((pos ^ ((r >> 1) & 3)) << 4)); }
                acc00 = mfma3216(a0, b0h, acc00);
                acc00 = mfma3216(a0, b0l, acc00);
                acc10 = mfma3216(a1, b0h, acc10);
                acc10 = mfma3216(a1, b0l, acc10);
            } else {
                short8v b0h, b0l, b1h, b1l;
                { const int r = wn * 64 + lane31;
                  b0h = *(const short8v*)((char*)Bsh + r * 64 + ((pos ^ ((r >> 1) & 3)) << 4));
                  b0l = *(const short8v*)((char*)Bsl + r * 64 + ((pos ^ ((r >> 1) & 3)) << 4)); }
                { const int r = wn * 64 + 32 + lane31;
                  b1h = *(const short8v*)((char*)Bsh + r * 64 + ((pos ^ ((r >> 1) & 3)) << 4));
                  b1l = *(const short8v*)((char*)Bsl + r * 64 + ((pos ^ ((r >> 1) & 3)) << 4)); }
                acc00 = mfma3216(a0, b0h, acc00);
                acc00 = mfma3216(a0, b0l, acc00);
                acc01 = mfma3216(a0, b1h, acc01);
                acc01 = mfma3216(a0, b1l, acc01);
                acc10 = mfma3216(a1, b0h, acc10);
                acc10 = mfma3216(a1, b0l, acc10);
                acc11 = mfma3216(a1, b1h, acc11);
                acc11 = mfma3216(a1, b1l, acc11);
            }
        }
        __syncthreads();
    }

    // ---- epilogue
    const int nb = n0 + wn * (BN / 2) + lane31;
#pragma unroll
    for (int r = 0; r < 16; ++r) {
        const int row = (r & 3) + 8 * (r >> 2) + 4 * hi8;
        store_c<MODE>(outb, outf, m0 + wm * 64 + row,      nb, acc00[r] + bias[nb]);
        store_c<MODE>(outb, outf, m0 + wm * 64 + 32 + row, nb, acc10[r] + bias[nb]);
        if constexpr (BN == 128) {
            store_c<MODE>(outb, outf, m0 + wm * 64 + row,      nb + 32, acc01[r] + bias[nb + 32]);
            store_c<MODE>(outb, outf, m0 + wm * 64 + 32 + row, nb + 32, acc11[r] + bias[nb + 32]);
        }
    }
}

__global__ __launch_bounds__(256) void qkv_gemm(
    const float* __restrict__ q, const float* __restrict__ k, const float* __restrict__ v,
    const unsigned short* __restrict__ Wh, const unsigned short* __restrict__ Wl,
    const float* __restrict__ bq, const float* __restrict__ bk, const float* __restrict__ bv,
    unsigned short* __restrict__ Qh, unsigned short* __restrict__ Kf,
    unsigned short* __restrict__ Vf)
{
    const int z = blockIdx.z;
    if (z == 0)      gemm_body<1, true, 128>(q, Wh,          Wl,          bq, Qh, nullptr);
    else if (z == 1) gemm_body<3, true, 128>(k, Wh + 262144, Wl + 262144, bk, Kf, nullptr);
    else             gemm_body<4, true, 128>(v, Wh + 524288, Wl + 524288, bv, Vf, nullptr);
}

__global__ __launch_bounds__(256) void out_gemm(
    const unsigned short* __restrict__ A,
    const unsigned short* __restrict__ Bh, const unsigned short* __restrict__ Bl,
    const float* __restrict__ bias, float* __restrict__ out)
{
    gemm_body<0, false, 64>(A, Bh, Bl, bias, nullptr, out);
}

// ---------------------------------------------------------------------------
// MFMA attention, single-QK^T design: QK^T + exp computed ONCE (pass 1),
// P cached in registers as bf16 pairs (pbuf[16][8] u32, statically indexed,
// fully unrolled — NOT the convicted load-ping-pong structure). Pass 2
// applies the threshold by exact bf16->f32 bit-unpack + f32 compare, then
// the unchanged shfl+select repack and PV MFMA.
// lsum/thr bit-identical to r6; P values bit-identical; only threshold
// decisions within bf16-rounding of thr may flip (est. impact ~3e-5/flip).
// Block = 4 waves, 32 q-rows of one (b,h); each wave a 512-key quarter.
// ---------------------------------------------------------------------------
__global__ __launch_bounds__(256) void attn_kernel(
    const unsigned short* __restrict__ Qh, const unsigned short* __restrict__ Kf,
    const unsigned short* __restrict__ Vf, unsigned short* __restrict__ concat)
{
    __shared__ float lds_l[4][32];
    __shared__ float lds_out[3][32][64];

    const int bid = blockIdx.x;
    const int xcd = bid & 7;
    const int j   = bid >> 3;
    const int bh  = 2 * xcd + (j >> 6);
    const int qt  = j & 63;

    const int tid    = threadIdx.x;
    const int w      = tid >> 6;
    const int l      = tid & 63;
    const int lane31 = l & 31;
    const int hi     = l >> 5;

    const int q0 = qt * 32;
    const unsigned short* Qb = Qh + ((size_t)bh * T_ + q0) * DK_;

    // Q B-fragments: col = lane31 (query), k = d = c*16 + hi*8 + {0..7}
    short8v qf[4];
#pragma unroll
    for (int c = 0; c < 4; ++c)
        qf[c] = *(const short8v*)(Qb + (size_t)lane31 * DK_ + c * 16 + hi * 8);

    // fragment-major bases for this wave's 16 tiles (keys w*512 .. w*512+511)
    const unsigned short* Kw = Kf + ((size_t)bh * 64 + w * 16) * 2048 + hi * 256 + lane31 * 8;
    const unsigned short* Vw = Vf + ((size_t)bh * 64 + w * 16) * 2048 + hi * 256 + lane31 * 8;

    // ---- pass 1: QK^T + exp once; accumulate lsum (r6 serial order);
    //      pack P = bf16(e) pairs into registers.
    unsigned pbuf[16][8];
    float lsum = 0.f;
#pragma unroll
    for (int kt = 0; kt < 16; ++kt) {
        const unsigned short* Kt = Kw + kt * 2048;
        short8v kf[4];
#pragma unroll
        for (int c = 0; c < 4; ++c)
            kf[c] = *(const short8v*)(Kt + c * 512);
        f32x16 acc = {};
#pragma unroll
        for (int c = 0; c < 4; ++c)
            acc = mfma3216(kf[c], qf[c], acc);
        float p[16];
#pragma unroll
        for (int r = 0; r < 16; ++r) {
            const float e = __expf(acc[r]);
            lsum += e;
            p[r] = e;
        }
#pragma unroll
        for (int i = 0; i < 8; ++i)
            pbuf[kt][i] = pk2(p[2 * i], p[2 * i + 1]);
    }
    lsum += __shfl_xor(lsum, 32);
    if (l < 32) lds_l[w][l] = lsum;
    __syncthreads();
    const float ltot = lds_l[0][lane31] + lds_l[1][lane31]
                     + lds_l[2][lane31] + lds_l[3][lane31];
    const float thr = ltot * (1.0f / 2048.0f);   // e > thr  <=>  p > row mean (=1/T)
    const float inv = 1.0f / ltot;

    // ---- pass 2: threshold cached P (exact bf16->f32 unpack, f32 compare),
    //      repack via shfl+select (unchanged), PV MFMA. No K reads, no exp.
    f32x16 o0 = {}, o1 = {};
#pragma unroll
    for (int kt = 0; kt < 16; ++kt) {
        unsigned t[8];
#pragma unroll
        for (int i = 0; i < 8; ++i) {
            const unsigned x = pbuf[kt][i];
            const float flo = __builtin_bit_cast(float, x << 16);
            const float fhi = __builtin_bit_cast(float, x & 0xffff0000u);
            unsigned r = 0;
            if (flo > thr) r = x & 0xffffu;
            if (fhi > thr) r |= x & 0xffff0000u;
            t[i] = r;
        }

        short8v pa[2];
#pragma unroll
        for (int h = 0; h < 2; ++h) {
            const unsigned a  = t[4 * h + 0];
            const unsigned b2 = t[4 * h + 1];
            const unsigned c2 = t[4 * h + 2];
            const unsigned d2 = t[4 * h + 3];
            const unsigned sa = (unsigned)__shfl_xor((int)a,  32);
            const unsigned sb = (unsigned)__shfl_xor((int)b2, 32);
            const unsigned sc = (unsigned)__shfl_xor((int)c2, 32);
            const unsigned sd = (unsigned)__shfl_xor((int)d2, 32);
            union { unsigned w2[4]; short8v v8; } u;
            u.w2[0] = hi ? sc : a;
            u.w2[1] = hi ? sd : b2;
            u.w2[2] = hi ? c2 : sa;
            u.w2[3] = hi ? d2 : sb;
            pa[h] = u.v8;
        }

        const unsigned short* Vt_ = Vw + kt * 2048;
#pragma unroll
        for (int h = 0; h < 2; ++h) {
            short8v vf0 = *(const short8v*)(Vt_ + (2 * h)     * 512);
            short8v vf1 = *(const short8v*)(Vt_ + (2 * h + 1) * 512);
            o0 = mfma3216(pa[h], vf0, o0);
            o1 = mfma3216(pa[h], vf1, o1);
        }
    }

    // ---- combine 4 key-quarters via LDS, scale by 1/l, store bf16
    if (w) {
#pragma unroll
        for (int r = 0; r < 16; ++r) {
            const int row = (r & 3) + 8 * (r >> 2) + 4 * hi;
            lds_out[w - 1][row][lane31]      = o0[r];
            lds_out[w - 1][row][32 + lane31] = o1[r];
        }
    }
    __syncthreads();
    if (!w) {
        const int b = bh >> 3, h = bh & 7;
        unsigned short* Cb = concat + ((size_t)b * T_ + q0) * DOUT + h * DK_;
#pragma unroll
        for (int r = 0; r < 16; ++r) {
            const int row = (r & 3) + 8 * (r >> 2) + 4 * hi;
            const float iv = __shfl(inv, row);
            const float v0 = o0[r] + lds_out[0][row][lane31]
                           + lds_out[1][row][lane31] + lds_out[2][row][lane31];
            const float v1 = o1[r] + lds_out[0][row][32 + lane31]
                           + lds_out[1][row][32 + lane31] + lds_out[2][row][32 + lane31];
            Cb[(size_t)row * DOUT + lane31]      = bf16c(v0 * iv);
            Cb[(size_t)row * DOUT + 32 + lane31] = bf16c(v1 * iv);
        }
    }
}

// ---------------------------------------------------------------------------
extern "C" void kernel_launch(void* const* d_in, const int* in_sizes, int n_in,
                              void* d_out, int out_size, void* d_ws, size_t ws_size,
                              hipStream_t stream)
{
    const float* q  = (const float*)d_in[0];
    const float* k  = (const float*)d_in[1];
    const float* v  = (const float*)d_in[2];
    const float* Wq = (const float*)d_in[3];
    const float* bq = (const float*)d_in[4];
    const float* Wk = (const float*)d_in[5];
    const float* bk = (const float*)d_in[6];
    const float* Wv = (const float*)d_in[7];
    const float* bv = (const float*)d_in[8];
    const float* Wo = (const float*)d_in[9];
    const float* bo = (const float*)d_in[10];
    float* out = (float*)d_out;

    constexpr size_t M2 = 2097152;  // 2M elements
    unsigned short* ws     = (unsigned short*)d_ws;
    unsigned short* Qh     = ws;
    unsigned short* Kf     = ws + 1 * M2;
    unsigned short* Vf     = ws + 2 * M2;
    unsigned short* concat = ws + 3 * M2;
    unsigned short* Wh     = ws + 4 * M2;        // 4 x 256K
    unsigned short* Wl     = ws + 4 * M2 + 1048576;

    wconvert_kernel<<<256, 256, 0, stream>>>(Wq, Wk, Wv, Wo, Wh, Wl);
    qkv_gemm<<<dim3(4, 32, 3), 256, 0, stream>>>(q, k, v, Wh, Wl, bq, bk, bv, Qh, Kf, Vf);
    attn_kernel<<<dim3(1024), 256, 0, stream>>>(Qh, Kf, Vf, concat);
    out_gemm<<<dim3(8, 32), 256, 0, stream>>>(concat, Wh + 786432, Wl + 786432, bo, out);
}

// Round 11
// 90.400 us; speedup vs baseline: 1.1269x; 1.1269x over previous
//
#include <hip/hip_runtime.h>

// B=2, T=2048, D_IN=D_OUT=512, H=8, DK=64
constexpr int B_   = 2;
constexpr int T_   = 2048;
constexpr int DIN  = 512;
constexpr int DOUT = 512;
constexpr int H_   = 8;
constexpr int DK_  = 64;

typedef float    f32x16  __attribute__((ext_vector_type(16)));
typedef short    short8v __attribute__((ext_vector_type(8)));
typedef __bf16   bf16x8  __attribute__((ext_vector_type(8)));

__device__ inline f32x16 mfma3216(short8v a, short8v b, f32x16 c) {
    return __builtin_amdgcn_mfma_f32_32x32x16_bf16(
        __builtin_bit_cast(bf16x8, a), __builtin_bit_cast(bf16x8, b), c, 0, 0, 0);
}

__device__ inline unsigned short bf16c(float f) {
    return __builtin_bit_cast(unsigned short, (__bf16)f);
}
__device__ inline float bf2f(unsigned short u) {
    return (float)__builtin_bit_cast(__bf16, u);
}
__device__ inline unsigned pk2(float lo, float hi) {
    return (unsigned)bf16c(lo) | ((unsigned)bf16c(hi) << 16);
}

// ---------------------------------------------------------------------------
// Weight conversion only: Wq,Wk,Wv,Wo f32 -> bf16 hi + bf16 lo. 256 blocks.
// (r6 verbatim)
// ---------------------------------------------------------------------------
__global__ __launch_bounds__(256) void wconvert_kernel(
    const float* __restrict__ Wq, const float* __restrict__ Wk,
    const float* __restrict__ Wv, const float* __restrict__ Wo,
    unsigned short* __restrict__ Wh, unsigned short* __restrict__ Wl)
{
    const int b = blockIdx.x, t = threadIdx.x;
    const int wi = b >> 6;
    const float* src = wi == 0 ? Wq : (wi == 1 ? Wk : (wi == 2 ? Wv : Wo));
    unsigned short* hi = Wh + (size_t)wi * 262144;
    unsigned short* lo = Wl + (size_t)wi * 262144;
    const size_t off = (size_t)(b & 63) * 4096;
#pragma unroll
    for (int c = 0; c < 4; ++c) {
        const size_t idx = off + (size_t)c * 1024 + (size_t)t * 4;
        const float4 x = *(const float4*)&src[idx];
        ushort4 h;
        h.x = bf16c(x.x); h.y = bf16c(x.y); h.z = bf16c(x.z); h.w = bf16c(x.w);
        *(ushort4*)&hi[idx] = h;
        ushort4 l2;
        l2.x = bf16c(x.x - bf2f(h.x));
        l2.y = bf16c(x.y - bf2f(h.y));
        l2.z = bf16c(x.z - bf2f(h.z));
        l2.w = bf16c(x.w - bf2f(h.w));
        *(ushort4*)&lo[idx] = l2;
    }
}

// ---------------------------------------------------------------------------
// Epilogue store: MODE 0 f32 [M,N]; 1 bf16 [B,H,T,DK]; 3 K-frag; 4 V-frag.
// ---------------------------------------------------------------------------
template<int MODE>
__device__ __forceinline__ void store_c(unsigned short* __restrict__ outb,
                                        float* __restrict__ outf,
                                        int m, int n, float v)
{
    if constexpr (MODE == 0) {
        outf[(size_t)m * DOUT + n] = v;
    } else {
        const int bb = m >> 11, t = m & (T_ - 1);
        const int hh = n >> 6,  d = n & (DK_ - 1);
        const size_t bh = (size_t)bb * H_ + hh;
        if constexpr (MODE == 1) {
            outb[(bh * T_ + t) * DK_ + d] = bf16c(v);
        } else if constexpr (MODE == 3) {
            // K-frag: [bh][kt][c*2+khi][l31][8]
            const int kt = t >> 5, l31 = t & 31;
            const int c = d >> 4, khi = (d >> 3) & 1, e = d & 7;
            outb[(bh * 64 + kt) * 2048 + (c * 2 + khi) * 256 + l31 * 8 + e] = bf16c(v);
        } else {
            // V-frag: [bh][kt][(kgrp*2+dblk)*2+khi][l31][8]
            const int kt = t >> 5, kgrp = (t >> 4) & 1, khi = (t >> 3) & 1, e = t & 7;
            const int dblk = d >> 5, l31 = d & 31;
            outb[(bh * 64 + kt) * 2048 + ((kgrp * 2 + dblk) * 2 + khi) * 256 + l31 * 8 + e] = bf16c(v);
        }
    }
}

// ---------------------------------------------------------------------------
// MFMA GEMM (r7 form — proven bit-neutral): out = A @ (Wh+Wl)^T + bias.
// BM=128, BN=64 or 128, BK=32, 4 waves. Single LDS buffer, two barriers per
// K-step, reg-prefetch of step kb+1. LDS XOR-swizzle pos ^= (row>>1)&3.
// ---------------------------------------------------------------------------
template<int MODE, bool AF32, int BN>
__device__ inline void gemm_body(
    const void* __restrict__ Av, const unsigned short* __restrict__ Bhp,
    const unsigned short* __restrict__ Blp, const float* __restrict__ bias,
    unsigned short* __restrict__ outb, float* __restrict__ outf)
{
    __shared__ unsigned short As[128 * 32];
    __shared__ unsigned short Bsh[BN * 32];
    __shared__ unsigned short Bsl[BN * 32];

    const int tid = threadIdx.x;
    const int m0 = blockIdx.y * 128, n0 = blockIdx.x * BN;
    const int lane31 = tid & 31, hi8 = (tid & 63) >> 5;
    const int wv = tid >> 6, wm = wv >> 1, wn = wv & 1;

    const int r_  = tid >> 2, pos_ = tid & 3;
    const int r2_ = r_ + 64;
    const int sw_  = pos_ ^ ((r_  >> 1) & 3);
    const int sw2_ = pos_ ^ ((r2_ >> 1) & 3);

    short8v a0r, a1r, bh0r, bl0r, bh1r, bl1r;

    auto gload = [&](int kb) {
        const int k0 = kb * 32;
        if constexpr (AF32) {
            const float* Af = (const float*)Av;
            {
                const float4 f0 = *(const float4*)&Af[(size_t)(m0 + r_) * DIN + k0 + pos_ * 8];
                const float4 f1 = *(const float4*)&Af[(size_t)(m0 + r_) * DIN + k0 + pos_ * 8 + 4];
                union { unsigned w[4]; short8v v; } u;
                u.w[0] = pk2(f0.x, f0.y); u.w[1] = pk2(f0.z, f0.w);
                u.w[2] = pk2(f1.x, f1.y); u.w[3] = pk2(f1.z, f1.w);
                a0r = u.v;
            }
            {
                const float4 f0 = *(const float4*)&Af[(size_t)(m0 + r2_) * DIN + k0 + pos_ * 8];
                const float4 f1 = *(const float4*)&Af[(size_t)(m0 + r2_) * DIN + k0 + pos_ * 8 + 4];
                union { unsigned w[4]; short8v v; } u;
                u.w[0] = pk2(f0.x, f0.y); u.w[1] = pk2(f0.z, f0.w);
                u.w[2] = pk2(f1.x, f1.y); u.w[3] = pk2(f1.z, f1.w);
                a1r = u.v;
            }
        } else {
            const unsigned short* Ab = (const unsigned short*)Av;
            a0r = *(const short8v*)&Ab[(size_t)(m0 + r_)  * DIN + k0 + pos_ * 8];
            a1r = *(const short8v*)&Ab[(size_t)(m0 + r2_) * DIN + k0 + pos_ * 8];
        }
        bh0r = *(const short8v*)&Bhp[(size_t)(n0 + r_) * DIN + k0 + pos_ * 8];
        bl0r = *(const short8v*)&Blp[(size_t)(n0 + r_) * DIN + k0 + pos_ * 8];
        if constexpr (BN == 128) {
            bh1r = *(const short8v*)&Bhp[(size_t)(n0 + r2_) * DIN + k0 + pos_ * 8];
            bl1r = *(const short8v*)&Blp[(size_t)(n0 + r2_) * DIN + k0 + pos_ * 8];
        }
    };
    auto swrite = [&]() {
        *(short8v*)((char*)As + r_  * 64 + sw_  * 16) = a0r;
        *(short8v*)((char*)As + r2_ * 64 + sw2_ * 16) = a1r;
        *(short8v*)((char*)Bsh + r_ * 64 + sw_ * 16) = bh0r;
        *(short8v*)((char*)Bsl + r_ * 64 + sw_ * 16) = bl0r;
        if constexpr (BN == 128) {
            *(short8v*)((char*)Bsh + r2_ * 64 + sw2_ * 16) = bh1r;
            *(short8v*)((char*)Bsl + r2_ * 64 + sw2_ * 16) = bl1r;
        }
    };

    f32x16 acc00 = {}, acc01 = {}, acc10 = {}, acc11 = {};

    gload(0);
    for (int kb = 0; kb < 16; ++kb) {
        swrite();
        __syncthreads();
        if (kb < 15) gload(kb + 1);       // prefetch next step during compute
#pragma unroll
        for (int ks = 0; ks < 2; ++ks) {
            const int pos = ks * 2 + hi8;
            short8v a0, a1;
            { const int r = wm * 64 + lane31;
              a0 = *(const short8v*)((char*)As + r * 64 + ((pos ^ ((r >> 1) & 3)) << 4)); }
            { const int r = wm * 64 + 32 + lane31;
              a1 = *(const short8v*)((char*)As + r * 64 + ((pos ^ ((r >> 1) & 3)) << 4)); }
            if constexpr (BN == 64) {
                short8v b0h, b0l;
                { const int r = wn * 32 + lane31;
                  b0h = *(const short8v*)((char*)Bsh + r * 64 + ((pos ^ ((r >> 1) & 3)) << 4));
                  b0l = *(const short8v*)((char*)Bsl + r * 64 + ((pos ^ ((r >> 1) & 3)) << 4)); }
                acc00 = mfma3216(a0, b0h, acc00);
                acc00 = mfma3216(a0, b0l, acc00);
                acc10 = mfma3216(a1, b0h, acc10);
                acc10 = mfma3216(a1, b0l, acc10);
            } else {
                short8v b0h, b0l, b1h, b1l;
                { const int r = wn * 64 + lane31;
                  b0h = *(const short8v*)((char*)Bsh + r * 64 + ((pos ^ ((r >> 1) & 3)) << 4));
                  b0l = *(const short8v*)((char*)Bsl + r * 64 + ((pos ^ ((r >> 1) & 3)) << 4)); }
                { const int r = wn * 64 + 32 + lane31;
                  b1h = *(const short8v*)((char*)Bsh + r * 64 + ((pos ^ ((r >> 1) & 3)) << 4));
                  b1l = *(const short8v*)((char*)Bsl + r * 64 + ((pos ^ ((r >> 1) & 3)) << 4)); }
                acc00 = mfma3216(a0, b0h, acc00);
                acc00 = mfma3216(a0, b0l, acc00);
                acc01 = mfma3216(a0, b1h, acc01);
                acc01 = mfma3216(a0, b1l, acc01);
                acc10 = mfma3216(a1, b0h, acc10);
                acc10 = mfma3216(a1, b0l, acc10);
                acc11 = mfma3216(a1, b1h, acc11);
                acc11 = mfma3216(a1, b1l, acc11);
            }
        }
        __syncthreads();
    }

    // ---- epilogue
    const int nb = n0 + wn * (BN / 2) + lane31;
#pragma unroll
    for (int r = 0; r < 16; ++r) {
        const int row = (r & 3) + 8 * (r >> 2) + 4 * hi8;
        store_c<MODE>(outb, outf, m0 + wm * 64 + row,      nb, acc00[r] + bias[nb]);
        store_c<MODE>(outb, outf, m0 + wm * 64 + 32 + row, nb, acc10[r] + bias[nb]);
        if constexpr (BN == 128) {
            store_c<MODE>(outb, outf, m0 + wm * 64 + row,      nb + 32, acc01[r] + bias[nb + 32]);
            store_c<MODE>(outb, outf, m0 + wm * 64 + 32 + row, nb + 32, acc11[r] + bias[nb + 32]);
        }
    }
}

__global__ __launch_bounds__(256) void qkv_gemm(
    const float* __restrict__ q, const float* __restrict__ k, const float* __restrict__ v,
    const unsigned short* __restrict__ Wh, const unsigned short* __restrict__ Wl,
    const float* __restrict__ bq, const float* __restrict__ bk, const float* __restrict__ bv,
    unsigned short* __restrict__ Qh, unsigned short* __restrict__ Kf,
    unsigned short* __restrict__ Vf)
{
    const int z = blockIdx.z;
    if (z == 0)      gemm_body<1, true, 128>(q, Wh,          Wl,          bq, Qh, nullptr);
    else if (z == 1) gemm_body<3, true, 128>(k, Wh + 262144, Wl + 262144, bk, Kf, nullptr);
    else             gemm_body<4, true, 128>(v, Wh + 524288, Wl + 524288, bv, Vf, nullptr);
}

__global__ __launch_bounds__(256) void out_gemm(
    const unsigned short* __restrict__ A,
    const unsigned short* __restrict__ Bh, const unsigned short* __restrict__ Bl,
    const float* __restrict__ bias, float* __restrict__ out)
{
    gemm_body<0, false, 64>(A, Bh, Bl, bias, nullptr, out);
}

// ---------------------------------------------------------------------------
// MFMA two-pass attention — r9 numeric structure (exp twice, f32 threshold,
// shfl+select repack; P-register-cache ABANDONED after r10 occupancy cliff),
// now with 8 waves/block + 8-way key split for 8 waves/SIMD (VGPR ~64).
// Cross-wave O combine is 2-stage through a 4-buffer 32KB LDS region so LDS
// doesn't cap occupancy. Block = 8 waves, 32 q-rows; each wave 256 keys.
// ---------------------------------------------------------------------------
__global__ __launch_bounds__(512) void attn_kernel(
    const unsigned short* __restrict__ Qh, const unsigned short* __restrict__ Kf,
    const unsigned short* __restrict__ Vf, unsigned short* __restrict__ concat)
{
    __shared__ float lds_l[8][32];
    __shared__ float lds_out[4][32][64];   // 32 KB, two-stage combine

    const int bid = blockIdx.x;
    const int xcd = bid & 7;
    const int j   = bid >> 3;
    const int bh  = 2 * xcd + (j >> 6);
    const int qt  = j & 63;

    const int tid    = threadIdx.x;
    const int w      = tid >> 6;         // 0..7: key octant
    const int l      = tid & 63;
    const int lane31 = l & 31;
    const int hi     = l >> 5;

    const int q0 = qt * 32;
    const unsigned short* Qb = Qh + ((size_t)bh * T_ + q0) * DK_;

    // Q B-fragments: col = lane31 (query), k = d = c*16 + hi*8 + {0..7}
    short8v qf[4];
#pragma unroll
    for (int c = 0; c < 4; ++c)
        qf[c] = *(const short8v*)(Qb + (size_t)lane31 * DK_ + c * 16 + hi * 8);

    // fragment-major bases for this wave's 8 tiles (keys w*256 .. w*256+255)
    const unsigned short* Kw = Kf + ((size_t)bh * 64 + w * 8) * 2048 + hi * 256 + lane31 * 8;
    const unsigned short* Vw = Vf + ((size_t)bh * 64 + w * 8) * 2048 + hi * 256 + lane31 * 8;

    // ---- pass 1: denominators
    float lsum = 0.f;
    for (int kt = 0; kt < 8; ++kt) {
        const unsigned short* Kt = Kw + kt * 2048;
        short8v kf[4];
#pragma unroll
        for (int c = 0; c < 4; ++c)
            kf[c] = *(const short8v*)(Kt + c * 512);
        f32x16 acc = {};
#pragma unroll
        for (int c = 0; c < 4; ++c)
            acc = mfma3216(kf[c], qf[c], acc);
#pragma unroll
        for (int r = 0; r < 16; ++r)
            lsum += __expf(acc[r]);
    }
    lsum += __shfl_xor(lsum, 32);
    if (l < 32) lds_l[w][l] = lsum;
    __syncthreads();
    float ltot = 0.f;
#pragma unroll
    for (int i = 0; i < 8; ++i) ltot += lds_l[i][lane31];
    const float thr = ltot * (1.0f / 2048.0f);   // e > thr  <=>  p > row mean (=1/T)
    const float inv = 1.0f / ltot;

    // ---- pass 2: masked PV (r9 per-element math)
    f32x16 o0 = {}, o1 = {};
    for (int kt = 0; kt < 8; ++kt) {
        const unsigned short* Kt = Kw + kt * 2048;
        short8v kf[4];
#pragma unroll
        for (int c = 0; c < 4; ++c)
            kf[c] = *(const short8v*)(Kt + c * 512);
        f32x16 acc = {};
#pragma unroll
        for (int c = 0; c < 4; ++c)
            acc = mfma3216(kf[c], qf[c], acc);

        float p[16];
#pragma unroll
        for (int r = 0; r < 16; ++r) {
            const float e = __expf(acc[r]);
            p[r] = (e > thr) ? e : 0.f;
        }

        // repack S^T (key split {0-3,8-11,..}+4hi) -> PV A-frag (keys 8hi..8hi+7)
        short8v pa[2];
#pragma unroll
        for (int h = 0; h < 2; ++h) {
            const unsigned a  = pk2(p[8 * h + 0], p[8 * h + 1]);
            const unsigned b2 = pk2(p[8 * h + 2], p[8 * h + 3]);
            const unsigned c2 = pk2(p[8 * h + 4], p[8 * h + 5]);
            const unsigned d2 = pk2(p[8 * h + 6], p[8 * h + 7]);
            const unsigned sa = (unsigned)__shfl_xor((int)a,  32);
            const unsigned sb = (unsigned)__shfl_xor((int)b2, 32);
            const unsigned sc = (unsigned)__shfl_xor((int)c2, 32);
            const unsigned sd = (unsigned)__shfl_xor((int)d2, 32);
            union { unsigned w2[4]; short8v v8; } u;
            u.w2[0] = hi ? sc : a;
            u.w2[1] = hi ? sd : b2;
            u.w2[2] = hi ? c2 : sa;
            u.w2[3] = hi ? d2 : sb;
            pa[h] = u.v8;
        }

        const unsigned short* Vt_ = Vw + kt * 2048;
#pragma unroll
        for (int h = 0; h < 2; ++h) {
            short8v vf0 = *(const short8v*)(Vt_ + (2 * h)     * 512);
            short8v vf1 = *(const short8v*)(Vt_ + (2 * h + 1) * 512);
            o0 = mfma3216(pa[h], vf0, o0);
            o1 = mfma3216(pa[h], vf1, o1);
        }
    }

    // ---- two-stage combine of 8 key-octants via 4 LDS buffers
    // stage 1: waves 4..7 publish; waves 0..3 absorb
    if (w >= 4) {
#pragma unroll
        for (int r = 0; r < 16; ++r) {
            const int row = (r & 3) + 8 * (r >> 2) + 4 * hi;
            lds_out[w - 4][row][lane31]      = o0[r];
            lds_out[w - 4][row][32 + lane31] = o1[r];
        }
    }
    __syncthreads();
    if (w < 4) {
#pragma unroll
        for (int r = 0; r < 16; ++r) {
            const int row = (r & 3) + 8 * (r >> 2) + 4 * hi;
            o0[r] += lds_out[w][row][lane31];
            o1[r] += lds_out[w][row][32 + lane31];
        }
    }
    __syncthreads();
    // stage 2: waves 1..3 publish; wave 0 finishes
    if (w >= 1 && w < 4) {
#pragma unroll
        for (int r = 0; r < 16; ++r) {
            const int row = (r & 3) + 8 * (r >> 2) + 4 * hi;
            lds_out[w - 1][row][lane31]      = o0[r];
            lds_out[w - 1][row][32 + lane31] = o1[r];
        }
    }
    __syncthreads();
    if (w == 0) {
        const int b = bh >> 3, h = bh & 7;
        unsigned short* Cb = concat + ((size_t)b * T_ + q0) * DOUT + h * DK_;
#pragma unroll
        for (int r = 0; r < 16; ++r) {
            const int row = (r & 3) + 8 * (r >> 2) + 4 * hi;
            const float iv = __shfl(inv, row);
            const float v0 = o0[r] + lds_out[0][row][lane31]
                           + lds_out[1][row][lane31] + lds_out[2][row][lane31];
            const float v1 = o1[r] + lds_out[0][row][32 + lane31]
                           + lds_out[1][row][32 + lane31] + lds_out[2][row][32 + lane31];
            Cb[(size_t)row * DOUT + lane31]      = bf16c(v0 * iv);
            Cb[(size_t)row * DOUT + 32 + lane31] = bf16c(v1 * iv);
        }
    }
}

// ---------------------------------------------------------------------------
extern "C" void kernel_launch(void* const* d_in, const int* in_sizes, int n_in,
                              void* d_out, int out_size, void* d_ws, size_t ws_size,
                              hipStream_t stream)
{
    const float* q  = (const float*)d_in[0];
    const float* k  = (const float*)d_in[1];
    const float* v  = (const float*)d_in[2];
    const float* Wq = (const float*)d_in[3];
    const float* bq = (const float*)d_in[4];
    const float* Wk = (const float*)d_in[5];
    const float* bk = (const float*)d_in[6];
    const float* Wv = (const float*)d_in[7];
    const float* bv = (const float*)d_in[8];
    const float* Wo = (const float*)d_in[9];
    const float* bo = (const float*)d_in[10];
    float* out = (float*)d_out;

    constexpr size_t M2 = 2097152;  // 2M elements
    unsigned short* ws     = (unsigned short*)d_ws;
    unsigned short* Qh     = ws;
    unsigned short* Kf     = ws + 1 * M2;
    unsigned short* Vf     = ws + 2 * M2;
    unsigned short* concat = ws + 3 * M2;
    unsigned short* Wh     = ws + 4 * M2;        // 4 x 256K
    unsigned short* Wl     = ws + 4 * M2 + 1048576;

    wconvert_kernel<<<256, 256, 0, stream>>>(Wq, Wk, Wv, Wo, Wh, Wl);
    qkv_gemm<<<dim3(4, 32, 3), 256, 0, stream>>>(q, k, v, Wh, Wl, bq, bk, bv, Qh, Kf, Vf);
    attn_kernel<<<dim3(1024), 512, 0, stream>>>(Qh, Kf, Vf, concat);
    out_gemm<<<dim3(8, 32), 256, 0, stream>>>(concat, Wh + 786432, Wl + 786432, bo, out);
}

// Round 12
// 88.815 us; speedup vs baseline: 1.1470x; 1.0178x over previous
//
#include <hip/hip_runtime.h>

// B=2, T=2048, D_IN=D_OUT=512, H=8, DK=64
constexpr int B_   = 2;
constexpr int T_   = 2048;
constexpr int DIN  = 512;
constexpr int DOUT = 512;
constexpr int H_   = 8;
constexpr int DK_  = 64;

constexpr float LOG2E = 1.44269504088896340736f;

typedef float    f32x16  __attribute__((ext_vector_type(16)));
typedef short    short8v __attribute__((ext_vector_type(8)));
typedef __bf16   bf16x8  __attribute__((ext_vector_type(8)));

__device__ inline f32x16 mfma3216(short8v a, short8v b, f32x16 c) {
    return __builtin_amdgcn_mfma_f32_32x32x16_bf16(
        __builtin_bit_cast(bf16x8, a), __builtin_bit_cast(bf16x8, b), c, 0, 0, 0);
}

__device__ inline unsigned short bf16c(float f) {
    return __builtin_bit_cast(unsigned short, (__bf16)f);
}
__device__ inline float bf2f(unsigned short u) {
    return (float)__builtin_bit_cast(__bf16, u);
}
__device__ inline unsigned pk2(float lo, float hi) {
    return (unsigned)bf16c(lo) | ((unsigned)bf16c(hi) << 16);
}
// swap: x'[32:63] = y[0:31], y'[0:31] = x[32:63]  (lane-exact match to the
// shfl_xor+select repack; bit-identity proven by r4/r5 output equality)
__device__ __forceinline__ void pl32swap(unsigned &x, unsigned &y) {
    asm("v_permlane32_swap_b32 %0, %1" : "+v"(x), "+v"(y));
}

// ---------------------------------------------------------------------------
// Weight conversion: Wq,Wk,Wv,Wo f32 -> bf16 hi + bf16 lo. Wq scaled by
// log2(e) so attention can use raw v_exp_f32 (2^x) instead of mul+exp.
// ---------------------------------------------------------------------------
__global__ __launch_bounds__(256) void wconvert_kernel(
    const float* __restrict__ Wq, const float* __restrict__ Wk,
    const float* __restrict__ Wv, const float* __restrict__ Wo,
    unsigned short* __restrict__ Wh, unsigned short* __restrict__ Wl)
{
    const int b = blockIdx.x, t = threadIdx.x;
    const int wi = b >> 6;
    const float* src = wi == 0 ? Wq : (wi == 1 ? Wk : (wi == 2 ? Wv : Wo));
    unsigned short* hi = Wh + (size_t)wi * 262144;
    unsigned short* lo = Wl + (size_t)wi * 262144;
    const float scl = (wi == 0) ? LOG2E : 1.0f;
    const size_t off = (size_t)(b & 63) * 4096;
#pragma unroll
    for (int c = 0; c < 4; ++c) {
        const size_t idx = off + (size_t)c * 1024 + (size_t)t * 4;
        float4 x = *(const float4*)&src[idx];
        x.x *= scl; x.y *= scl; x.z *= scl; x.w *= scl;
        ushort4 h;
        h.x = bf16c(x.x); h.y = bf16c(x.y); h.z = bf16c(x.z); h.w = bf16c(x.w);
        *(ushort4*)&hi[idx] = h;
        ushort4 l2;
        l2.x = bf16c(x.x - bf2f(h.x));
        l2.y = bf16c(x.y - bf2f(h.y));
        l2.z = bf16c(x.z - bf2f(h.z));
        l2.w = bf16c(x.w - bf2f(h.w));
        *(ushort4*)&lo[idx] = l2;
    }
}

// ---------------------------------------------------------------------------
// Epilogue store: MODE 0 f32 [M,N]; 1 bf16 [B,H,T,DK]; 3 K-frag; 4 V-frag.
// ---------------------------------------------------------------------------
template<int MODE>
__device__ __forceinline__ void store_c(unsigned short* __restrict__ outb,
                                        float* __restrict__ outf,
                                        int m, int n, float v)
{
    if constexpr (MODE == 0) {
        outf[(size_t)m * DOUT + n] = v;
    } else {
        const int bb = m >> 11, t = m & (T_ - 1);
        const int hh = n >> 6,  d = n & (DK_ - 1);
        const size_t bh = (size_t)bb * H_ + hh;
        if constexpr (MODE == 1) {
            outb[(bh * T_ + t) * DK_ + d] = bf16c(v);
        } else if constexpr (MODE == 3) {
            // K-frag: [bh][kt][c*2+khi][l31][8]
            const int kt = t >> 5, l31 = t & 31;
            const int c = d >> 4, khi = (d >> 3) & 1, e = d & 7;
            outb[(bh * 64 + kt) * 2048 + (c * 2 + khi) * 256 + l31 * 8 + e] = bf16c(v);
        } else {
            // V-frag: [bh][kt][(kgrp*2+dblk)*2+khi][l31][8]
            const int kt = t >> 5, kgrp = (t >> 4) & 1, khi = (t >> 3) & 1, e = t & 7;
            const int dblk = d >> 5, l31 = d & 31;
            outb[(bh * 64 + kt) * 2048 + ((kgrp * 2 + dblk) * 2 + khi) * 256 + l31 * 8 + e] = bf16c(v);
        }
    }
}

// ---------------------------------------------------------------------------
// MFMA GEMM (r7 form — proven bit-neutral): out = A @ (Wh+Wl)^T + bias*bscale.
// BM=128, BN=64 or 128, BK=32, 4 waves. Single LDS buffer, two barriers per
// K-step, reg-prefetch of step kb+1. LDS XOR-swizzle pos ^= (row>>1)&3.
// ---------------------------------------------------------------------------
template<int MODE, bool AF32, int BN>
__device__ inline void gemm_body(
    const void* __restrict__ Av, const unsigned short* __restrict__ Bhp,
    const unsigned short* __restrict__ Blp, const float* __restrict__ bias,
    float bscale,
    unsigned short* __restrict__ outb, float* __restrict__ outf)
{
    __shared__ unsigned short As[128 * 32];
    __shared__ unsigned short Bsh[BN * 32];
    __shared__ unsigned short Bsl[BN * 32];

    const int tid = threadIdx.x;
    const int m0 = blockIdx.y * 128, n0 = blockIdx.x * BN;
    const int lane31 = tid & 31, hi8 = (tid & 63) >> 5;
    const int wv = tid >> 6, wm = wv >> 1, wn = wv & 1;

    const int r_  = tid >> 2, pos_ = tid & 3;
    const int r2_ = r_ + 64;
    const int sw_  = pos_ ^ ((r_  >> 1) & 3);
    const int sw2_ = pos_ ^ ((r2_ >> 1) & 3);

    short8v a0r, a1r, bh0r, bl0r, bh1r, bl1r;

    auto gload = [&](int kb) {
        const int k0 = kb * 32;
        if constexpr (AF32) {
            const float* Af = (const float*)Av;
            {
                const float4 f0 = *(const float4*)&Af[(size_t)(m0 + r_) * DIN + k0 + pos_ * 8];
                const float4 f1 = *(const float4*)&Af[(size_t)(m0 + r_) * DIN + k0 + pos_ * 8 + 4];
                union { unsigned w[4]; short8v v; } u;
                u.w[0] = pk2(f0.x, f0.y); u.w[1] = pk2(f0.z, f0.w);
                u.w[2] = pk2(f1.x, f1.y); u.w[3] = pk2(f1.z, f1.w);
                a0r = u.v;
            }
            {
                const float4 f0 = *(const float4*)&Af[(size_t)(m0 + r2_) * DIN + k0 + pos_ * 8];
                const float4 f1 = *(const float4*)&Af[(size_t)(m0 + r2_) * DIN + k0 + pos_ * 8 + 4];
                union { unsigned w[4]; short8v v; } u;
                u.w[0] = pk2(f0.x, f0.y); u.w[1] = pk2(f0.z, f0.w);
                u.w[2] = pk2(f1.x, f1.y); u.w[3] = pk2(f1.z, f1.w);
                a1r = u.v;
            }
        } else {
            const unsigned short* Ab = (const unsigned short*)Av;
            a0r = *(const short8v*)&Ab[(size_t)(m0 + r_)  * DIN + k0 + pos_ * 8];
            a1r = *(const short8v*)&Ab[(size_t)(m0 + r2_) * DIN + k0 + pos_ * 8];
        }
        bh0r = *(const short8v*)&Bhp[(size_t)(n0 + r_) * DIN + k0 + pos_ * 8];
        bl0r = *(const short8v*)&Blp[(size_t)(n0 + r_) * DIN + k0 + pos_ * 8];
        if constexpr (BN == 128) {
            bh1r = *(const short8v*)&Bhp[(size_t)(n0 + r2_) * DIN + k0 + pos_ * 8];
            bl1r = *(const short8v*)&Blp[(size_t)(n0 + r2_) * DIN + k0 + pos_ * 8];
        }
    };
    auto swrite = [&]() {
        *(short8v*)((char*)As + r_  * 64 + sw_  * 16) = a0r;
        *(short8v*)((char*)As + r2_ * 64 + sw2_ * 16) = a1r;
        *(short8v*)((char*)Bsh + r_ * 64 + sw_ * 16) = bh0r;
        *(short8v*)((char*)Bsl + r_ * 64 + sw_ * 16) = bl0r;
        if constexpr (BN == 128) {
            *(short8v*)((char*)Bsh + r2_ * 64 + sw2_ * 16) = bh1r;
            *(short8v*)((char*)Bsl + r2_ * 64 + sw2_ * 16) = bl1r;
        }
    };

    f32x16 acc00 = {}, acc01 = {}, acc10 = {}, acc11 = {};

    gload(0);
    for (int kb = 0; kb < 16; ++kb) {
        swrite();
        __syncthreads();
        if (kb < 15) gload(kb + 1);       // prefetch next step during compute
#pragma unroll
        for (int ks = 0; ks < 2; ++ks) {
            const int pos = ks * 2 + hi8;
            short8v a0, a1;
            { const int r = wm * 64 + lane31;
              a0 = *(const short8v*)((char*)As + r * 64 + ((pos ^ ((r >> 1) & 3)) << 4)); }
            { const int r = wm * 64 + 32 + lane31;
              a1 = *(const short8v*)((char*)As + r * 64 + ((pos ^ ((r >> 1) & 3)) << 4)); }
            if constexpr (BN == 64) {
                short8v b0h, b0l;
                { const int r = wn * 32 + lane31;
                  b0h = *(const short8v*)((char*)Bsh + r * 64 + ((pos ^ ((r >> 1) & 3)) << 4));
                  b0l = *(const short8v*)((char*)Bsl + r * 64 + ((pos ^ ((r >> 1) & 3)) << 4)); }
                acc00 = mfma3216(a0, b0h, acc00);
                acc00 = mfma3216(a0, b0l, acc00);
                acc10 = mfma3216(a1, b0h, acc10);
                acc10 = mfma3216(a1, b0l, acc10);
            } else {
                short8v b0h, b0l, b1h, b1l;
                { const int r = wn * 64 + lane31;
                  b0h = *(const short8v*)((char*)Bsh + r * 64 + ((pos ^ ((r >> 1) & 3)) << 4));
                  b0l = *(const short8v*)((char*)Bsl + r * 64 + ((pos ^ ((r >> 1) & 3)) << 4)); }
                { const int r = wn * 64 + 32 + lane31;
                  b1h = *(const short8v*)((char*)Bsh + r * 64 + ((pos ^ ((r >> 1) & 3)) << 4));
                  b1l = *(const short8v*)((char*)Bsl + r * 64 + ((pos ^ ((r >> 1) & 3)) << 4)); }
                acc00 = mfma3216(a0, b0h, acc00);
                acc00 = mfma3216(a0, b0l, acc00);
                acc01 = mfma3216(a0, b1h, acc01);
                acc01 = mfma3216(a0, b1l, acc01);
                acc10 = mfma3216(a1, b0h, acc10);
                acc10 = mfma3216(a1, b0l, acc10);
                acc11 = mfma3216(a1, b1h, acc11);
                acc11 = mfma3216(a1, b1l, acc11);
            }
        }
        __syncthreads();
    }

    // ---- epilogue
    const int nb = n0 + wn * (BN / 2) + lane31;
#pragma unroll
    for (int r = 0; r < 16; ++r) {
        const int row = (r & 3) + 8 * (r >> 2) + 4 * hi8;
        store_c<MODE>(outb, outf, m0 + wm * 64 + row,      nb, acc00[r] + bias[nb] * bscale);
        store_c<MODE>(outb, outf, m0 + wm * 64 + 32 + row, nb, acc10[r] + bias[nb] * bscale);
        if constexpr (BN == 128) {
            store_c<MODE>(outb, outf, m0 + wm * 64 + row,      nb + 32, acc01[r] + bias[nb + 32] * bscale);
            store_c<MODE>(outb, outf, m0 + wm * 64 + 32 + row, nb + 32, acc11[r] + bias[nb + 32] * bscale);
        }
    }
}

__global__ __launch_bounds__(256) void qkv_gemm(
    const float* __restrict__ q, const float* __restrict__ k, const float* __restrict__ v,
    const unsigned short* __restrict__ Wh, const unsigned short* __restrict__ Wl,
    const float* __restrict__ bq, const float* __restrict__ bk, const float* __restrict__ bv,
    unsigned short* __restrict__ Qh, unsigned short* __restrict__ Kf,
    unsigned short* __restrict__ Vf)
{
    const int z = blockIdx.z;
    if (z == 0)      gemm_body<1, true, 128>(q, Wh,          Wl,          bq, LOG2E, Qh, nullptr);
    else if (z == 1) gemm_body<3, true, 128>(k, Wh + 262144, Wl + 262144, bk, 1.0f,  Kf, nullptr);
    else             gemm_body<4, true, 128>(v, Wh + 524288, Wl + 524288, bv, 1.0f,  Vf, nullptr);
}

__global__ __launch_bounds__(256) void out_gemm(
    const unsigned short* __restrict__ A,
    const unsigned short* __restrict__ Bh, const unsigned short* __restrict__ Bl,
    const float* __restrict__ bias, float* __restrict__ out)
{
    gemm_body<0, false, 64>(A, Bh, Bl, bias, 1.0f, nullptr, out);
}

// ---------------------------------------------------------------------------
// MFMA two-pass attention — r11 structure (8 waves, 8-way key split, 2-stage
// LDS combine) with per-wave op-count cuts:
//   * Q pre-scaled by log2e -> exp is a single v_exp_f32 (exp2)
//   * permlane32_swap repack (replaces 8 ds_bpermute + 8 selects with 4 VALU)
//   * 4-way partial lsum (breaks 128-deep serial fadd chain)
//   * s_setprio(1) around MFMA clusters
// ---------------------------------------------------------------------------
__global__ __launch_bounds__(512) void attn_kernel(
    const unsigned short* __restrict__ Qh, const unsigned short* __restrict__ Kf,
    const unsigned short* __restrict__ Vf, unsigned short* __restrict__ concat)
{
    __shared__ float lds_l[8][32];
    __shared__ float lds_out[4][32][64];   // 32 KB, two-stage combine

    const int bid = blockIdx.x;
    const int xcd = bid & 7;
    const int j   = bid >> 3;
    const int bh  = 2 * xcd + (j >> 6);
    const int qt  = j & 63;

    const int tid    = threadIdx.x;
    const int w      = tid >> 6;         // 0..7: key octant
    const int l      = tid & 63;
    const int lane31 = l & 31;
    const int hi     = l >> 5;

    const int q0 = qt * 32;
    const unsigned short* Qb = Qh + ((size_t)bh * T_ + q0) * DK_;

    // Q B-fragments: col = lane31 (query), k = d = c*16 + hi*8 + {0..7}
    short8v qf[4];
#pragma unroll
    for (int c = 0; c < 4; ++c)
        qf[c] = *(const short8v*)(Qb + (size_t)lane31 * DK_ + c * 16 + hi * 8);

    // fragment-major bases for this wave's 8 tiles (keys w*256 .. w*256+255)
    const unsigned short* Kw = Kf + ((size_t)bh * 64 + w * 8) * 2048 + hi * 256 + lane31 * 8;
    const unsigned short* Vw = Vf + ((size_t)bh * 64 + w * 8) * 2048 + hi * 256 + lane31 * 8;

    // ---- pass 1: denominators (exp2; 4 partial sums)
    float ls0 = 0.f, ls1 = 0.f, ls2 = 0.f, ls3 = 0.f;
    for (int kt = 0; kt < 8; ++kt) {
        const unsigned short* Kt = Kw + kt * 2048;
        short8v kf[4];
#pragma unroll
        for (int c = 0; c < 4; ++c)
            kf[c] = *(const short8v*)(Kt + c * 512);
        f32x16 acc = {};
        __builtin_amdgcn_s_setprio(1);
#pragma unroll
        for (int c = 0; c < 4; ++c)
            acc = mfma3216(kf[c], qf[c], acc);
        __builtin_amdgcn_s_setprio(0);
#pragma unroll
        for (int r = 0; r < 16; r += 4) {
            ls0 += __builtin_amdgcn_exp2f(acc[r + 0]);
            ls1 += __builtin_amdgcn_exp2f(acc[r + 1]);
            ls2 += __builtin_amdgcn_exp2f(acc[r + 2]);
            ls3 += __builtin_amdgcn_exp2f(acc[r + 3]);
        }
    }
    float lsum = (ls0 + ls1) + (ls2 + ls3);
    lsum += __shfl_xor(lsum, 32);
    if (l < 32) lds_l[w][l] = lsum;
    __syncthreads();
    float ltot = 0.f;
#pragma unroll
    for (int i = 0; i < 8; ++i) ltot += lds_l[i][lane31];
    const float thr = ltot * (1.0f / 2048.0f);   // e > thr  <=>  p > row mean (=1/T)
    const float inv = 1.0f / ltot;

    // ---- pass 2: masked PV (exp2, permlane repack)
    f32x16 o0 = {}, o1 = {};
    for (int kt = 0; kt < 8; ++kt) {
        const unsigned short* Kt = Kw + kt * 2048;
        short8v kf[4];
#pragma unroll
        for (int c = 0; c < 4; ++c)
            kf[c] = *(const short8v*)(Kt + c * 512);
        f32x16 acc = {};
        __builtin_amdgcn_s_setprio(1);
#pragma unroll
        for (int c = 0; c < 4; ++c)
            acc = mfma3216(kf[c], qf[c], acc);
        __builtin_amdgcn_s_setprio(0);

        float p[16];
#pragma unroll
        for (int r = 0; r < 16; ++r) {
            const float e = __builtin_amdgcn_exp2f(acc[r]);
            p[r] = (e > thr) ? e : 0.f;
        }

        // repack S^T -> PV A-frag via permlane32_swap (lane-exact match to
        // the shfl_xor+select form; proven bit-identical by r4/r5 equality)
        short8v pa[2];
#pragma unroll
        for (int h = 0; h < 2; ++h) {
            unsigned a  = pk2(p[8 * h + 0], p[8 * h + 1]);
            unsigned b2 = pk2(p[8 * h + 2], p[8 * h + 3]);
            unsigned c2 = pk2(p[8 * h + 4], p[8 * h + 5]);
            unsigned d2 = pk2(p[8 * h + 6], p[8 * h + 7]);
            pl32swap(a, c2);
            pl32swap(b2, d2);
            union { unsigned w2[4]; short8v v8; } u;
            u.w2[0] = a; u.w2[1] = b2; u.w2[2] = c2; u.w2[3] = d2;
            pa[h] = u.v8;
        }

        const unsigned short* Vt_ = Vw + kt * 2048;
        short8v vf0 = *(const short8v*)(Vt_);
        short8v vf1 = *(const short8v*)(Vt_ + 512);
        short8v vf2 = *(const short8v*)(Vt_ + 1024);
        short8v vf3 = *(const short8v*)(Vt_ + 1536);
        __builtin_amdgcn_s_setprio(1);
        o0 = mfma3216(pa[0], vf0, o0);
        o1 = mfma3216(pa[0], vf1, o1);
        o0 = mfma3216(pa[1], vf2, o0);
        o1 = mfma3216(pa[1], vf3, o1);
        __builtin_amdgcn_s_setprio(0);
    }

    // ---- two-stage combine of 8 key-octants via 4 LDS buffers
    if (w >= 4) {
#pragma unroll
        for (int r = 0; r < 16; ++r) {
            const int row = (r & 3) + 8 * (r >> 2) + 4 * hi;
            lds_out[w - 4][row][lane31]      = o0[r];
            lds_out[w - 4][row][32 + lane31] = o1[r];
        }
    }
    __syncthreads();
    if (w < 4) {
#pragma unroll
        for (int r = 0; r < 16; ++r) {
            const int row = (r & 3) + 8 * (r >> 2) + 4 * hi;
            o0[r] += lds_out[w][row][lane31];
            o1[r] += lds_out[w][row][32 + lane31];
        }
    }
    __syncthreads();
    if (w >= 1 && w < 4) {
#pragma unroll
        for (int r = 0; r < 16; ++r) {
            const int row = (r & 3) + 8 * (r >> 2) + 4 * hi;
            lds_out[w - 1][row][lane31]      = o0[r];
            lds_out[w - 1][row][32 + lane31] = o1[r];
        }
    }
    __syncthreads();
    if (w == 0) {
        const int b = bh >> 3, h = bh & 7;
        unsigned short* Cb = concat + ((size_t)b * T_ + q0) * DOUT + h * DK_;
#pragma unroll
        for (int r = 0; r < 16; ++r) {
            const int row = (r & 3) + 8 * (r >> 2) + 4 * hi;
            const float iv = __shfl(inv, row);
            const float v0 = o0[r] + lds_out[0][row][lane31]
                           + lds_out[1][row][lane31] + lds_out[2][row][lane31];
            const float v1 = o1[r] + lds_out[0][row][32 + lane31]
                           + lds_out[1][row][32 + lane31] + lds_out[2][row][32 + lane31];
            Cb[(size_t)row * DOUT + lane31]      = bf16c(v0 * iv);
            Cb[(size_t)row * DOUT + 32 + lane31] = bf16c(v1 * iv);
        }
    }
}

// ---------------------------------------------------------------------------
extern "C" void kernel_launch(void* const* d_in, const int* in_sizes, int n_in,
                              void* d_out, int out_size, void* d_ws, size_t ws_size,
                              hipStream_t stream)
{
    const float* q  = (const float*)d_in[0];
    const float* k  = (const float*)d_in[1];
    const float* v  = (const float*)d_in[2];
    const float* Wq = (const float*)d_in[3];
    const float* bq = (const float*)d_in[4];
    const float* Wk = (const float*)d_in[5];
    const float* bk = (const float*)d_in[6];
    const float* Wv = (const float*)d_in[7];
    const float* bv = (const float*)d_in[8];
    const float* Wo = (const float*)d_in[9];
    const float* bo = (const float*)d_in[10];
    float* out = (float*)d_out;

    constexpr size_t M2 = 2097152;  // 2M elements
    unsigned short* ws     = (unsigned short*)d_ws;
    unsigned short* Qh     = ws;
    unsigned short* Kf     = ws + 1 * M2;
    unsigned short* Vf     = ws + 2 * M2;
    unsigned short* concat = ws + 3 * M2;
    unsigned short* Wh     = ws + 4 * M2;        // 4 x 256K
    unsigned short* Wl     = ws + 4 * M2 + 1048576;

    wconvert_kernel<<<256, 256, 0, stream>>>(Wq, Wk, Wv, Wo, Wh, Wl);
    qkv_gemm<<<dim3(4, 32, 3), 256, 0, stream>>>(q, k, v, Wh, Wl, bq, bk, bv, Qh, Kf, Vf);
    attn_kernel<<<dim3(1024), 512, 0, stream>>>(Qh, Kf, Vf, concat);
    out_gemm<<<dim3(8, 32), 256, 0, stream>>>(concat, Wh + 786432, Wl + 786432, bo, out);
}